// Round 1
// baseline (593.036 us; speedup 1.0000x reference)
//
#include <hip/hip_runtime.h>
#include <hip/hip_bf16.h>

typedef __attribute__((ext_vector_type(4))) float floatx4;
typedef __bf16 bf16x8 __attribute__((ext_vector_type(8)));

static __device__ __forceinline__ unsigned short f2bf(float x) {
    union { float f; unsigned int u; } v; v.f = x;
    unsigned int u = v.u;
    unsigned int r = u + 0x7FFF + ((u >> 16) & 1);   // round-to-nearest-even
    return (unsigned short)(r >> 16);
}

// Kernel 1 v2: per-node transform. 2 nodes/block.
//   support[k] = sum_j in[j] * W[n][j][k]
//   h[j]      = sum_k R[n][j][k] * support[k]
// Stage 2 restructured: 32 j-rows x 4 k-groups per node. Each thread does a
// register dot over a contiguous 128B chunk of row j (8 independent float4
// loads, s broadcast from LDS), then a 2-shuffle reduce across the 4 k-groups.
// Replaces the old per-iteration 5-deep shfl chain (160 shfl/thread -> 8).
// Writes h transposed as bf16: h_t[feature j][node n]
__global__ __launch_bounds__(256) void node_transform(
    const float* __restrict__ input,      // [4096][128]
    const float* __restrict__ rel,        // [4096][128][128]
    const float* __restrict__ wts,        // [4096][128][128]
    unsigned int* __restrict__ h_t)       // [128][2048] uint = [128][4096] bf16
{
    __shared__ float s_in[2][128];
    __shared__ float s_part[2][4][128];
    __shared__ float s_sup[2][128];
    __shared__ float s_h[2][128];

    const int tid = threadIdx.x;
    const int b = blockIdx.x;

    if (tid < 64) {
        float4 v = ((const float4*)input)[b * 64 + tid];
        ((float4*)&s_in[0][0])[tid] = v;
    }
    __syncthreads();

    const int node = tid >> 7;
    const int tl   = tid & 127;
    const int n    = b * 2 + node;

    // ---- stage 1: support = in^T * W ----
    {
        const int jg = tl >> 5;
        const int kq = tl & 31;
        const float4* W4 = (const float4*)(wts + (size_t)n * 16384);
        float4 acc = {0.f, 0.f, 0.f, 0.f};
        const int j0 = jg * 32;
        #pragma unroll 16
        for (int jj = 0; jj < 32; ++jj) {
            const int j = j0 + jj;
            const float x = s_in[node][j];
            const float4 w = W4[j * 32 + kq];
            acc.x += x * w.x; acc.y += x * w.y;
            acc.z += x * w.z; acc.w += x * w.w;
        }
        ((float4*)&s_part[node][jg][0])[kq] = acc;
    }
    __syncthreads();
    s_sup[node][tl] = s_part[node][0][tl] + s_part[node][1][tl]
                    + s_part[node][2][tl] + s_part[node][3][tl];
    __syncthreads();

    // ---- stage 2 (new): h = R * support, register dots ----
    {
        const int jl = tl >> 2;               // 0..31: j-row within pass
        const int kg = tl & 3;                // 0..3:  k-group (32 floats each)
        const float4* R4 = (const float4*)(rel + (size_t)n * 16384);
        const float4* S4 = (const float4*)&s_sup[node][0];
        // 4 passes x 32 rows = 128 rows. Per pass: 8 independent float4 loads
        // per thread covering bytes [kg*128, kg*128+128) of row j; lanes with
        // equal kg broadcast-read the same s_sup chunk (conflict-free).
        #pragma unroll 2
        for (int p = 0; p < 4; ++p) {
            const int j = p * 32 + jl;
            const float4* rr = R4 + j * 32 + kg * 8;
            float acc = 0.f;
            #pragma unroll
            for (int i = 0; i < 8; ++i) {
                const float4 r = rr[i];
                const float4 s = S4[kg * 8 + i];
                acc += r.x * s.x + r.y * s.y + r.z * s.z + r.w * s.w;
            }
            // reduce across kg (lanes j*4+0..3, 4-aligned within a wave)
            acc += __shfl_xor(acc, 1);
            acc += __shfl_xor(acc, 2);
            if (kg == 0) s_h[node][j] = acc;
        }
    }
    __syncthreads();

    if (tid < 128) {
        const unsigned int lo = f2bf(s_h[0][tid]);
        const unsigned int hi = f2bf(s_h[1][tid]);
        h_t[tid * 2048 + b] = lo | (hi << 16);
    }
}

// Kernel 2 (unchanged): partial[s] = adj[:, s*1024:(s+1)*1024] @ h[s*1024:(s+1)*1024, :]
// Split-K=4 LDS-staged bf16 MFMA. Grid 1024 = 256 row-tiles x 4 K-splits,
// 512 threads (8 waves, one 16x16 tile each). LDS 38.25 KB -> 4 blocks/CU,
// 32 waves/CU: barrier drains in one block overlap other blocks' compute.
__global__ __launch_bounds__(512) void agg_gemm_splitk(
    const float* __restrict__ A,              // [4096][4096] fp32 adjacency
    const unsigned short* __restrict__ ht,    // [128][4096] bf16 (h transposed)
    float* __restrict__ part)                 // [4][4096][128] fp32 partials
{
    __shared__ __align__(16) unsigned short As[16][136];
    __shared__ __align__(16) unsigned short Bs[128][136];

    const int tid  = threadIdx.x;
    const int wave = tid >> 6;                // 0..7 -> col group
    const int lane = tid & 63;
    const int s    = blockIdx.x & 3;          // K-split
    const int m0   = (blockIdx.x >> 2) * 16;  // row tile
    const int kbase = s * 1024;

    floatx4 acc = {0.f, 0.f, 0.f, 0.f};

    const int ar = tid >> 5;                  // A stage: row 0..15
    const int ac = (tid & 31) * 4;            //          col quad
    const int bj = tid >> 2;                  // B stage: feature row 0..127
    const int bs = tid & 3;                   //          16B sub-chunk

    for (int kb = kbase; kb < kbase + 1024; kb += 128) {
        __syncthreads();                      // protect LDS from previous iter reads
        // stage A tile: 16 x 128 fp32 -> bf16 (512 thr x 1 float4, coalesced)
        {
            const float4 v = *(const float4*)(A + (size_t)(m0 + ar) * 4096 + kb + ac);
            const unsigned int p0 = (unsigned int)f2bf(v.x) | ((unsigned int)f2bf(v.y) << 16);
            const unsigned int p1 = (unsigned int)f2bf(v.z) | ((unsigned int)f2bf(v.w) << 16);
            *(uint2*)&As[ar][ac] = make_uint2(p0, p1);
        }
        // stage B tile: 128 x 128 bf16 (512 thr x 4 uint4)
        {
            const unsigned short* src = ht + (size_t)bj * 4096 + kb + bs * 8;
            #pragma unroll
            for (int i = 0; i < 4; ++i) {
                const uint4 v = *(const uint4*)(src + i * 32);
                *(uint4*)&Bs[bj][bs * 8 + i * 32] = v;
            }
        }
        __syncthreads();
        // compute: wave covers cols [wave*16, wave*16+16)
        const int mn = lane & 15;             // A row m / B col n
        const int kq = lane >> 4;             // k-quad: 8 contiguous k per lane
        const unsigned short* arow = &As[mn][kq * 8];
        const unsigned short* brow = &Bs[wave * 16 + mn][kq * 8];
        #pragma unroll
        for (int k0 = 0; k0 < 128; k0 += 32) {
            const bf16x8 af  = *(const bf16x8*)(arow + k0);
            const bf16x8 bfr = *(const bf16x8*)(brow + k0);
            acc = __builtin_amdgcn_mfma_f32_16x16x32_bf16(af, bfr, acc, 0, 0, 0);
        }
    }

    // epilogue: C/D layout col=lane&15, row=(lane>>4)*4+reg
    const int col = wave * 16 + (lane & 15);
    const int r0  = (lane >> 4) * 4;
    float* dst = part + ((size_t)s * 4096 + m0 + r0) * 128 + col;
    #pragma unroll
    for (int r = 0; r < 4; ++r) {
        dst[(size_t)r * 128] = acc[r];
    }
}

// Kernel 3 (unchanged): out = sum_s part[s] + bias. 131072 float4s, 1 per thread.
__global__ __launch_bounds__(256) void reduce_bias(
    const float* __restrict__ part,           // [4][4096][128]
    const float* __restrict__ bias,           // [128]
    float* __restrict__ out)                  // [4096][128]
{
    const int f = blockIdx.x * 256 + threadIdx.x;   // float4 index, 0..131071
    const float4* p4 = (const float4*)part;
    const float4 b = ((const float4*)bias)[f & 31];
    float4 s0 = p4[f];
    float4 s1 = p4[131072 + f];
    float4 s2 = p4[262144 + f];
    float4 s3 = p4[393216 + f];
    float4 r;
    r.x = s0.x + s1.x + s2.x + s3.x + b.x;
    r.y = s0.y + s1.y + s2.y + s3.y + b.y;
    r.z = s0.z + s1.z + s2.z + s3.z + b.z;
    r.w = s0.w + s1.w + s2.w + s3.w + b.w;
    ((float4*)out)[f] = r;
}

extern "C" void kernel_launch(void* const* d_in, const int* in_sizes, int n_in,
                              void* d_out, int out_size, void* d_ws, size_t ws_size,
                              hipStream_t stream) {
    const float* input = (const float*)d_in[0];   // [4096][128]
    const float* adj   = (const float*)d_in[1];   // [4096][4096]
    const float* rel   = (const float*)d_in[2];   // [4096][128][128]
    const float* wts   = (const float*)d_in[3];   // [4096][128][128]
    const float* bias  = (const float*)d_in[4];   // [128]
    float* out = (float*)d_out;

    unsigned int* h_t = (unsigned int*)d_ws;              // 1 MB: bf16 h transposed [128][4096]
    float* part = (float*)((char*)d_ws + (1 << 20));      // 8 MB: fp32 partials [4][4096][128]

    node_transform<<<2048, 256, 0, stream>>>(input, rel, wts, h_t);
    agg_gemm_splitk<<<1024, 512, 0, stream>>>(adj, (const unsigned short*)d_ws, part);
    reduce_bias<<<512, 256, 0, stream>>>(part, bias, out);
}

// Round 2
// 570.019 us; speedup vs baseline: 1.0404x; 1.0404x over previous
//
#include <hip/hip_runtime.h>
#include <hip/hip_bf16.h>

typedef __attribute__((ext_vector_type(4))) float floatx4;
typedef __bf16 bf16x8 __attribute__((ext_vector_type(8)));

static __device__ __forceinline__ unsigned short f2bf(float x) {
    union { float f; unsigned int u; } v; v.f = x;
    unsigned int u = v.u;
    unsigned int r = u + 0x7FFF + ((u >> 16) & 1);   // round-to-nearest-even
    return (unsigned short)(r >> 16);
}

// Kernel 1 v3: per-node transform, 1 node per block, 256 threads.
//   support[k] = sum_j in[j] * W[n][j][k]
//   h[j]      = sum_k R[n][j][k] * support[k]
// All global loads fully coalesced (thread t reads float4 f = i*256+t, so a
// wave covers 1KB contiguous per instruction). No shuffle chains: stage-2
// partials go through a padded [128][33] LDS transpose-reduce (conflict-free
// writes; reads are 2-way = free). Writes h transposed bf16: h_t[j][n].
__global__ __launch_bounds__(256) void node_transform(
    const float* __restrict__ input,      // [4096][128]
    const float* __restrict__ rel,        // [4096][128][128]
    const float* __restrict__ wts,        // [4096][128][128]
    unsigned short* __restrict__ h_t)     // [128][4096] bf16 (h transposed)
{
    __shared__ float s_in[128];
    __shared__ float s_sup[128];
    __shared__ __align__(16) float s_big[4224];  // stage1: [8][128]; stage2: [128][33]

    const int tid = threadIdx.x;
    const int n   = blockIdx.x;
    const int l   = tid & 31;   // float4 column quad within a row
    const int g   = tid >> 5;   // 0..7: row group

    if (tid < 32) {
        ((float4*)s_in)[tid] = ((const float4*)(input + (size_t)n * 128))[tid];
    }
    __syncthreads();

    // ---- stage 1: support = in^T * W (coalesced, 4-col partial per thread) ----
    {
        const float4* W4 = (const float4*)(wts + (size_t)n * 16384);
        float4 acc = {0.f, 0.f, 0.f, 0.f};
        #pragma unroll 8
        for (int i = 0; i < 16; ++i) {
            const int j = i * 8 + g;            // f = i*256+tid -> row j, quad l
            const float  x = s_in[j];
            const float4 w = W4[i * 256 + tid];
            acc.x += x * w.x; acc.y += x * w.y;
            acc.z += x * w.z; acc.w += x * w.w;
        }
        ((float4*)&s_big[g * 128])[l] = acc;    // s_big[g][4l..4l+3]
    }
    __syncthreads();
    if (tid < 128) {
        float s = 0.f;
        #pragma unroll
        for (int g2 = 0; g2 < 8; ++g2) s += s_big[g2 * 128 + tid];
        s_sup[tid] = s;
    }
    __syncthreads();

    // ---- stage 2: h = R * support (coalesced loads, LDS transpose-reduce) ----
    {
        const float4* R4 = (const float4*)(rel + (size_t)n * 16384);
        const float4  sv = ((const float4*)s_sup)[l];
        #pragma unroll 8
        for (int i = 0; i < 16; ++i) {
            const int j = i * 8 + g;
            const float4 r = R4[i * 256 + tid];
            const float p = r.x * sv.x + r.y * sv.y + r.z * sv.z + r.w * sv.w;
            s_big[j * 33 + l] = p;              // padded: banks (j+l)%32 per half-wave
        }
    }
    __syncthreads();
    if (tid < 128) {
        float h = 0.f;
        #pragma unroll
        for (int m = 0; m < 32; ++m) h += s_big[tid * 33 + m];  // banks (tid+m)%32: 2-way
        h_t[(size_t)tid * 4096 + n] = f2bf(h);
    }
}

// Kernel 2 (unchanged): partial[s] = adj[:, s*1024:(s+1)*1024] @ h[s*1024:(s+1)*1024, :]
// Split-K=4 LDS-staged bf16 MFMA. Grid 1024 = 256 row-tiles x 4 K-splits,
// 512 threads (8 waves, one 16x16 tile each). LDS 38.25 KB -> 4 blocks/CU,
// 32 waves/CU: barrier drains in one block overlap other blocks' compute.
__global__ __launch_bounds__(512) void agg_gemm_splitk(
    const float* __restrict__ A,              // [4096][4096] fp32 adjacency
    const unsigned short* __restrict__ ht,    // [128][4096] bf16 (h transposed)
    float* __restrict__ part)                 // [4][4096][128] fp32 partials
{
    __shared__ __align__(16) unsigned short As[16][136];
    __shared__ __align__(16) unsigned short Bs[128][136];

    const int tid  = threadIdx.x;
    const int wave = tid >> 6;                // 0..7 -> col group
    const int lane = tid & 63;
    const int s    = blockIdx.x & 3;          // K-split
    const int m0   = (blockIdx.x >> 2) * 16;  // row tile
    const int kbase = s * 1024;

    floatx4 acc = {0.f, 0.f, 0.f, 0.f};

    const int ar = tid >> 5;                  // A stage: row 0..15
    const int ac = (tid & 31) * 4;            //          col quad
    const int bj = tid >> 2;                  // B stage: feature row 0..127
    const int bs = tid & 3;                   //          16B sub-chunk

    for (int kb = kbase; kb < kbase + 1024; kb += 128) {
        __syncthreads();                      // protect LDS from previous iter reads
        // stage A tile: 16 x 128 fp32 -> bf16 (512 thr x 1 float4, coalesced)
        {
            const float4 v = *(const float4*)(A + (size_t)(m0 + ar) * 4096 + kb + ac);
            const unsigned int p0 = (unsigned int)f2bf(v.x) | ((unsigned int)f2bf(v.y) << 16);
            const unsigned int p1 = (unsigned int)f2bf(v.z) | ((unsigned int)f2bf(v.w) << 16);
            *(uint2*)&As[ar][ac] = make_uint2(p0, p1);
        }
        // stage B tile: 128 x 128 bf16 (512 thr x 4 uint4)
        {
            const unsigned short* src = ht + (size_t)bj * 4096 + kb + bs * 8;
            #pragma unroll
            for (int i = 0; i < 4; ++i) {
                const uint4 v = *(const uint4*)(src + i * 32);
                *(uint4*)&Bs[bj][bs * 8 + i * 32] = v;
            }
        }
        __syncthreads();
        // compute: wave covers cols [wave*16, wave*16+16)
        const int mn = lane & 15;             // A row m / B col n
        const int kq = lane >> 4;             // k-quad: 8 contiguous k per lane
        const unsigned short* arow = &As[mn][kq * 8];
        const unsigned short* brow = &Bs[wave * 16 + mn][kq * 8];
        #pragma unroll
        for (int k0 = 0; k0 < 128; k0 += 32) {
            const bf16x8 af  = *(const bf16x8*)(arow + k0);
            const bf16x8 bfr = *(const bf16x8*)(brow + k0);
            acc = __builtin_amdgcn_mfma_f32_16x16x32_bf16(af, bfr, acc, 0, 0, 0);
        }
    }

    // epilogue: C/D layout col=lane&15, row=(lane>>4)*4+reg
    const int col = wave * 16 + (lane & 15);
    const int r0  = (lane >> 4) * 4;
    float* dst = part + ((size_t)s * 4096 + m0 + r0) * 128 + col;
    #pragma unroll
    for (int r = 0; r < 4; ++r) {
        dst[(size_t)r * 128] = acc[r];
    }
}

// Kernel 3 (unchanged): out = sum_s part[s] + bias. 131072 float4s, 1 per thread.
__global__ __launch_bounds__(256) void reduce_bias(
    const float* __restrict__ part,           // [4][4096][128]
    const float* __restrict__ bias,           // [128]
    float* __restrict__ out)                  // [4096][128]
{
    const int f = blockIdx.x * 256 + threadIdx.x;   // float4 index, 0..131071
    const float4* p4 = (const float4*)part;
    const float4 b = ((const float4*)bias)[f & 31];
    float4 s0 = p4[f];
    float4 s1 = p4[131072 + f];
    float4 s2 = p4[262144 + f];
    float4 s3 = p4[393216 + f];
    float4 r;
    r.x = s0.x + s1.x + s2.x + s3.x + b.x;
    r.y = s0.y + s1.y + s2.y + s3.y + b.y;
    r.z = s0.z + s1.z + s2.z + s3.z + b.z;
    r.w = s0.w + s1.w + s2.w + s3.w + b.w;
    ((float4*)out)[f] = r;
}

extern "C" void kernel_launch(void* const* d_in, const int* in_sizes, int n_in,
                              void* d_out, int out_size, void* d_ws, size_t ws_size,
                              hipStream_t stream) {
    const float* input = (const float*)d_in[0];   // [4096][128]
    const float* adj   = (const float*)d_in[1];   // [4096][4096]
    const float* rel   = (const float*)d_in[2];   // [4096][128][128]
    const float* wts   = (const float*)d_in[3];   // [4096][128][128]
    const float* bias  = (const float*)d_in[4];   // [128]
    float* out = (float*)d_out;

    unsigned short* h_t = (unsigned short*)d_ws;          // 1 MB: bf16 h transposed [128][4096]
    float* part = (float*)((char*)d_ws + (1 << 20));      // 8 MB: fp32 partials [4][4096][128]

    node_transform<<<4096, 256, 0, stream>>>(input, rel, wts, h_t);
    agg_gemm_splitk<<<1024, 512, 0, stream>>>(adj, (const unsigned short*)d_ws, part);
    reduce_bias<<<512, 256, 0, stream>>>(part, bias, out);
}